// Round 2
// baseline (72.888 us; speedup 1.0000x reference)
//
#include <hip/hip_runtime.h>
#include <cmath>

#define D 4096

typedef float fvec4 __attribute__((ext_vector_type(4)));

__device__ __forceinline__ float wave_reduce_sum(float v) {
#pragma unroll
    for (int off = 32; off > 0; off >>= 1)
        v += __shfl_down(v, off, 64);
    return v;
}

__device__ __forceinline__ float sigmoidf(float x) {
    return 1.0f / (1.0f + expf(-x));
}

// ws layout (floats):
//   [0 .. 4095]        q
//   [4096 .. 8191]     k (already scaled by 1/sqrt(D))
//   [8192 .. 12287]    v
//   [12288 .. 16383]   o = sigmoid(w_o@x + b_o)
//   [16384]            raw i dot (w_i@x + b_i)
//   [16385]            raw f dot (w_f@x + b_f)
//   [16386]            kq = k . q
//   [16387]            npq = n_prev . q
//   [16388 .. 20483]   cprevq[row] = c_prev[row,:] . q

// Kernel A: 4 fused matvecs (q,k,v,o) + i/f row dots. One wave per row.
__global__ __launch_bounds__(256) void gates_kernel(
    const float* __restrict__ x,
    const float* __restrict__ wq, const float* __restrict__ bq,
    const float* __restrict__ wk, const float* __restrict__ bk,
    const float* __restrict__ wv, const float* __restrict__ bv,
    const float* __restrict__ wi, const float* __restrict__ bi,
    const float* __restrict__ wf, const float* __restrict__ bfv,
    const float* __restrict__ wo, const float* __restrict__ bo,
    float* __restrict__ ws)
{
    __shared__ float xs[D];
    const int tid = threadIdx.x;
    fvec4* xs4 = (fvec4*)xs;
    const fvec4* x4 = (const fvec4*)x;
#pragma unroll
    for (int i = 0; i < 4; ++i) xs4[tid + i * 256] = x4[tid + i * 256];
    __syncthreads();

    const int wave = tid >> 6;
    const int lane = tid & 63;

    if (blockIdx.x == 4096) {
        // i_t and f_t raw dots (rows of w_i, w_f)
        if (wave < 2) {
            const fvec4* W4 = (const fvec4*)(wave == 0 ? wi : wf);
            float acc = 0.f;
#pragma unroll
            for (int it = 0; it < 16; ++it) {
                fvec4 w = W4[it * 64 + lane];
                fvec4 xv = xs4[it * 64 + lane];
                acc += w.x * xv.x + w.y * xv.y + w.z * xv.z + w.w * xv.w;
            }
            acc = wave_reduce_sum(acc);
            if (lane == 0) {
                float b = (wave == 0) ? bi[0] : bfv[0];
                ws[16384 + wave] = acc + b;
            }
        }
        return;
    }

    const int rid = blockIdx.x * 4 + wave;     // [0, 16384)
    const int m = rid >> 12;                   // which matrix
    const int row = rid & 4095;
    const float* W = (m == 0) ? wq : (m == 1) ? wk : (m == 2) ? wv : wo;
    const fvec4* W4 = (const fvec4*)(W + (size_t)row * D);
    float acc = 0.f;
#pragma unroll
    for (int it = 0; it < 16; ++it) {
        fvec4 w = __builtin_nontemporal_load(&W4[it * 64 + lane]);
        fvec4 xv = xs4[it * 64 + lane];
        acc += w.x * xv.x + w.y * xv.y + w.z * xv.z + w.w * xv.w;
    }
    acc = wave_reduce_sum(acc);
    if (lane == 0) {
        if (m == 0)      ws[row]         = acc + bq[row];
        else if (m == 1) ws[4096 + row]  = (acc + bk[row]) * 0.015625f; // 1/sqrt(4096)
        else if (m == 2) ws[8192 + row]  = acc + bv[row];
        else             ws[12288 + row] = sigmoidf(acc + bo[row]);
    }
}

// Kernel B: c_t = f*c_prev + i*v(x)k  streamed; fused per-row c_prev.q dot.
// Extra block (blockIdx==1024) computes kq and n_prev.q scalars.
__global__ __launch_bounds__(256) void cell_kernel(
    const float* __restrict__ c_prev,
    const float* __restrict__ n_prev,
    float* __restrict__ ws,
    float* __restrict__ c_out)
{
    const int tid = threadIdx.x;
    const int wave = tid >> 6;
    const int lane = tid & 63;

    if (blockIdx.x == 1024) {
        __shared__ float red[8];
        const fvec4* q4 = (const fvec4*)ws;
        const fvec4* k4 = (const fvec4*)(ws + D);
        const fvec4* np4 = (const fvec4*)n_prev;
        float kq = 0.f, npq = 0.f;
#pragma unroll
        for (int i = 0; i < 4; ++i) {
            int j = tid + i * 256;
            fvec4 q = q4[j], k = k4[j], np = np4[j];
            kq  += k.x * q.x + k.y * q.y + k.z * q.z + k.w * q.w;
            npq += np.x * q.x + np.y * q.y + np.z * q.z + np.w * q.w;
        }
        kq = wave_reduce_sum(kq);
        npq = wave_reduce_sum(npq);
        if (lane == 0) { red[wave] = kq; red[4 + wave] = npq; }
        __syncthreads();
        if (tid == 0) {
            ws[16386] = red[0] + red[1] + red[2] + red[3];
            ws[16387] = red[4] + red[5] + red[6] + red[7];
        }
        return;
    }

    __shared__ float ks[D];
    __shared__ float qs[D];
    fvec4* ks4 = (fvec4*)ks;
    fvec4* qs4 = (fvec4*)qs;
    const fvec4* k4g = (const fvec4*)(ws + D);
    const fvec4* q4g = (const fvec4*)ws;
#pragma unroll
    for (int i = 0; i < 4; ++i) {
        ks4[tid + i * 256] = k4g[tid + i * 256];
        qs4[tid + i * 256] = q4g[tid + i * 256];
    }
    __syncthreads();

    const float i_t = expf(ws[16384]);
    const float f_t = sigmoidf(ws[16385]);

    const int row = blockIdx.x * 4 + wave;     // [0, 4096)
    const float vr = ws[8192 + row] * i_t;     // i_t * v[row]
    const fvec4* cp4 = (const fvec4*)(c_prev + (size_t)row * D);
    fvec4* co4 = (fvec4*)(c_out + (size_t)row * D);
    float dot = 0.f;
#pragma unroll
    for (int it = 0; it < 16; ++it) {
        int j = it * 64 + lane;
        fvec4 cp = __builtin_nontemporal_load(&cp4[j]);
        fvec4 kk = ks4[j];
        fvec4 qq = qs4[j];
        fvec4 ct;
        ct.x = f_t * cp.x + vr * kk.x;
        ct.y = f_t * cp.y + vr * kk.y;
        ct.z = f_t * cp.z + vr * kk.z;
        ct.w = f_t * cp.w + vr * kk.w;
        __builtin_nontemporal_store(ct, &co4[j]);
        dot += cp.x * qq.x + cp.y * qq.y + cp.z * qq.z + cp.w * qq.w;
    }
    dot = wave_reduce_sum(dot);
    if (lane == 0) ws[16388 + row] = dot;
}

// Kernel C: n_t, h_t (4096 threads)
__global__ __launch_bounds__(256) void finalize_kernel(
    const float* __restrict__ n_prev,
    const float* __restrict__ ws,
    float* __restrict__ out)
{
    const int idx = blockIdx.x * 256 + threadIdx.x;
    const float i_t = expf(ws[16384]);
    const float f_t = sigmoidf(ws[16385]);
    const float kq  = ws[16386];
    const float npq = ws[16387];
    const float nqt = f_t * npq + i_t * kq;          // n_t . q
    const float inv = 1.0f / fmaxf(fabsf(nqt), 1.0f);

    const float k = ws[4096 + idx];
    const float v = ws[8192 + idx];
    const float o = ws[12288 + idx];
    const float cpq = ws[16388 + idx];

    const float h_tilde = (f_t * cpq + i_t * kq * v) * inv;
    out[idx] = o * h_tilde;                            // h_t
    out[(size_t)4096 + (size_t)D * D + idx] = f_t * n_prev[idx] + i_t * k;  // n_t
}

extern "C" void kernel_launch(void* const* d_in, const int* in_sizes, int n_in,
                              void* d_out, int out_size, void* d_ws, size_t ws_size,
                              hipStream_t stream)
{
    const float* x      = (const float*)d_in[0];
    const float* c_prev = (const float*)d_in[1];
    const float* n_prev = (const float*)d_in[2];
    const float* wq = (const float*)d_in[3];  const float* bq  = (const float*)d_in[4];
    const float* wk = (const float*)d_in[5];  const float* bk  = (const float*)d_in[6];
    const float* wv = (const float*)d_in[7];  const float* bv  = (const float*)d_in[8];
    const float* wi = (const float*)d_in[9];  const float* bi  = (const float*)d_in[10];
    const float* wf = (const float*)d_in[11]; const float* bfv = (const float*)d_in[12];
    const float* wo = (const float*)d_in[13]; const float* bo  = (const float*)d_in[14];
    float* out = (float*)d_out;
    float* ws  = (float*)d_ws;

    gates_kernel<<<dim3(4097), dim3(256), 0, stream>>>(
        x, wq, bq, wk, bk, wv, bv, wi, bi, wf, bfv, wo, bo, ws);
    cell_kernel<<<dim3(1025), dim3(256), 0, stream>>>(c_prev, n_prev, ws, out + D);
    finalize_kernel<<<dim3(16), dim3(256), 0, stream>>>(n_prev, ws, out);
}

// Round 3
// 71.454 us; speedup vs baseline: 1.0201x; 1.0201x over previous
//
#include <hip/hip_runtime.h>
#include <cmath>

#define D 4096

typedef float fvec4 __attribute__((ext_vector_type(4)));

__device__ __forceinline__ float wave_reduce_sum(float v) {
#pragma unroll
    for (int off = 32; off > 0; off >>= 1)
        v += __shfl_down(v, off, 64);
    return v;
}

__device__ __forceinline__ float sigmoidf(float x) {
    return 1.0f / (1.0f + expf(-x));
}

// ws layout (floats):
//   [0 .. 4095]        q
//   [4096 .. 8191]     k (already scaled by 1/sqrt(D))
//   [8192 .. 12287]    v
//   [12288 .. 16383]   o = sigmoid(w_o@x + b_o)
//   [16384]            raw i dot (w_i@x + b_i)
//   [16385]            raw f dot (w_f@x + b_f)
//   [16386]            kq = k . q
//   [16387]            npq = n_prev . q
//   [16388 .. 20483]   cprevq[row] = c_prev[row,:] . q

// Kernel A: 4 fused matvecs (q,k,v,o) + i/f row dots. One wave per row.
// Weights loaded with NORMAL (cacheable) loads so they stay L3-resident
// across graph replays; all 16 float4 row-loads hoisted into registers
// for maximal memory-level parallelism.
__global__ __launch_bounds__(256) void gates_kernel(
    const float* __restrict__ x,
    const float* __restrict__ wq, const float* __restrict__ bq,
    const float* __restrict__ wk, const float* __restrict__ bk,
    const float* __restrict__ wv, const float* __restrict__ bv,
    const float* __restrict__ wi, const float* __restrict__ bi,
    const float* __restrict__ wf, const float* __restrict__ bfv,
    const float* __restrict__ wo, const float* __restrict__ bo,
    float* __restrict__ ws)
{
    __shared__ float xs[D];
    const int tid = threadIdx.x;
    fvec4* xs4 = (fvec4*)xs;
    const fvec4* x4 = (const fvec4*)x;
#pragma unroll
    for (int i = 0; i < 4; ++i) xs4[tid + i * 256] = x4[tid + i * 256];
    __syncthreads();

    const int wave = tid >> 6;
    const int lane = tid & 63;

    if (blockIdx.x == 4096) {
        // i_t and f_t raw dots (rows of w_i, w_f)
        if (wave < 2) {
            const fvec4* W4 = (const fvec4*)(wave == 0 ? wi : wf);
            float acc = 0.f;
#pragma unroll
            for (int it = 0; it < 16; ++it) {
                fvec4 w = W4[it * 64 + lane];
                fvec4 xv = xs4[it * 64 + lane];
                acc += w.x * xv.x + w.y * xv.y + w.z * xv.z + w.w * xv.w;
            }
            acc = wave_reduce_sum(acc);
            if (lane == 0) {
                float b = (wave == 0) ? bi[0] : bfv[0];
                ws[16384 + wave] = acc + b;
            }
        }
        return;
    }

    const int rid = blockIdx.x * 4 + wave;     // [0, 16384)
    const int m = rid >> 12;                   // which matrix
    const int row = rid & 4095;
    const float* W = (m == 0) ? wq : (m == 1) ? wk : (m == 2) ? wv : wo;
    const fvec4* W4 = (const fvec4*)(W + (size_t)row * D);

    // Phase 1: issue all 16 row loads (16 KB/wave in flight).
    fvec4 w[16];
#pragma unroll
    for (int it = 0; it < 16; ++it)
        w[it] = W4[it * 64 + lane];

    // Phase 2: FMA against LDS-staged x (two acc chains to shorten deps).
    float acc0 = 0.f, acc1 = 0.f;
#pragma unroll
    for (int it = 0; it < 16; it += 2) {
        fvec4 xv0 = xs4[it * 64 + lane];
        fvec4 xv1 = xs4[(it + 1) * 64 + lane];
        acc0 += w[it].x * xv0.x + w[it].y * xv0.y + w[it].z * xv0.z + w[it].w * xv0.w;
        acc1 += w[it + 1].x * xv1.x + w[it + 1].y * xv1.y + w[it + 1].z * xv1.z + w[it + 1].w * xv1.w;
    }
    float acc = wave_reduce_sum(acc0 + acc1);
    if (lane == 0) {
        if (m == 0)      ws[row]         = acc + bq[row];
        else if (m == 1) ws[4096 + row]  = (acc + bk[row]) * 0.015625f; // 1/sqrt(4096)
        else if (m == 2) ws[8192 + row]  = acc + bv[row];
        else             ws[12288 + row] = sigmoidf(acc + bo[row]);
    }
}

// Kernel B: c_t = f*c_prev + i*v(x)k  streamed; fused per-row c_prev.q dot.
// c_prev/c_out stay NONTEMPORAL so the streaming traffic does not evict the
// weight matrices from L3. Extra block computes kq and n_prev.q scalars.
__global__ __launch_bounds__(256) void cell_kernel(
    const float* __restrict__ c_prev,
    const float* __restrict__ n_prev,
    float* __restrict__ ws,
    float* __restrict__ c_out)
{
    const int tid = threadIdx.x;
    const int wave = tid >> 6;
    const int lane = tid & 63;

    if (blockIdx.x == 1024) {
        __shared__ float red[8];
        const fvec4* q4 = (const fvec4*)ws;
        const fvec4* k4 = (const fvec4*)(ws + D);
        const fvec4* np4 = (const fvec4*)n_prev;
        float kq = 0.f, npq = 0.f;
#pragma unroll
        for (int i = 0; i < 4; ++i) {
            int j = tid + i * 256;
            fvec4 q = q4[j], k = k4[j], np = np4[j];
            kq  += k.x * q.x + k.y * q.y + k.z * q.z + k.w * q.w;
            npq += np.x * q.x + np.y * q.y + np.z * q.z + np.w * q.w;
        }
        kq = wave_reduce_sum(kq);
        npq = wave_reduce_sum(npq);
        if (lane == 0) { red[wave] = kq; red[4 + wave] = npq; }
        __syncthreads();
        if (tid == 0) {
            ws[16386] = red[0] + red[1] + red[2] + red[3];
            ws[16387] = red[4] + red[5] + red[6] + red[7];
        }
        return;
    }

    __shared__ float ks[D];
    __shared__ float qs[D];
    fvec4* ks4 = (fvec4*)ks;
    fvec4* qs4 = (fvec4*)qs;
    const fvec4* k4g = (const fvec4*)(ws + D);
    const fvec4* q4g = (const fvec4*)ws;
#pragma unroll
    for (int i = 0; i < 4; ++i) {
        ks4[tid + i * 256] = k4g[tid + i * 256];
        qs4[tid + i * 256] = q4g[tid + i * 256];
    }
    __syncthreads();

    const float i_t = expf(ws[16384]);
    const float f_t = sigmoidf(ws[16385]);

    const int row = blockIdx.x * 4 + wave;     // [0, 4096)
    const float vr = ws[8192 + row] * i_t;     // i_t * v[row]
    const fvec4* cp4 = (const fvec4*)(c_prev + (size_t)row * D);
    fvec4* co4 = (fvec4*)(c_out + (size_t)row * D);
    float dot = 0.f;
#pragma unroll
    for (int it = 0; it < 16; ++it) {
        int j = it * 64 + lane;
        fvec4 cp = __builtin_nontemporal_load(&cp4[j]);
        fvec4 kk = ks4[j];
        fvec4 qq = qs4[j];
        fvec4 ct;
        ct.x = f_t * cp.x + vr * kk.x;
        ct.y = f_t * cp.y + vr * kk.y;
        ct.z = f_t * cp.z + vr * kk.z;
        ct.w = f_t * cp.w + vr * kk.w;
        __builtin_nontemporal_store(ct, &co4[j]);
        dot += cp.x * qq.x + cp.y * qq.y + cp.z * qq.z + cp.w * qq.w;
    }
    dot = wave_reduce_sum(dot);
    if (lane == 0) ws[16388 + row] = dot;
}

// Kernel C: n_t, h_t (4096 threads)
__global__ __launch_bounds__(256) void finalize_kernel(
    const float* __restrict__ n_prev,
    const float* __restrict__ ws,
    float* __restrict__ out)
{
    const int idx = blockIdx.x * 256 + threadIdx.x;
    const float i_t = expf(ws[16384]);
    const float f_t = sigmoidf(ws[16385]);
    const float kq  = ws[16386];
    const float npq = ws[16387];
    const float nqt = f_t * npq + i_t * kq;          // n_t . q
    const float inv = 1.0f / fmaxf(fabsf(nqt), 1.0f);

    const float k = ws[4096 + idx];
    const float v = ws[8192 + idx];
    const float o = ws[12288 + idx];
    const float cpq = ws[16388 + idx];

    const float h_tilde = (f_t * cpq + i_t * kq * v) * inv;
    out[idx] = o * h_tilde;                            // h_t
    out[(size_t)4096 + (size_t)D * D + idx] = f_t * n_prev[idx] + i_t * k;  // n_t
}

extern "C" void kernel_launch(void* const* d_in, const int* in_sizes, int n_in,
                              void* d_out, int out_size, void* d_ws, size_t ws_size,
                              hipStream_t stream)
{
    const float* x      = (const float*)d_in[0];
    const float* c_prev = (const float*)d_in[1];
    const float* n_prev = (const float*)d_in[2];
    const float* wq = (const float*)d_in[3];  const float* bq  = (const float*)d_in[4];
    const float* wk = (const float*)d_in[5];  const float* bk  = (const float*)d_in[6];
    const float* wv = (const float*)d_in[7];  const float* bv  = (const float*)d_in[8];
    const float* wi = (const float*)d_in[9];  const float* bi  = (const float*)d_in[10];
    const float* wf = (const float*)d_in[11]; const float* bfv = (const float*)d_in[12];
    const float* wo = (const float*)d_in[13]; const float* bo  = (const float*)d_in[14];
    float* out = (float*)d_out;
    float* ws  = (float*)d_ws;

    gates_kernel<<<dim3(4097), dim3(256), 0, stream>>>(
        x, wq, bq, wk, bk, wv, bv, wi, bi, wf, bfv, wo, bo, ws);
    cell_kernel<<<dim3(1025), dim3(256), 0, stream>>>(c_prev, n_prev, ws, out + D);
    finalize_kernel<<<dim3(16), dim3(256), 0, stream>>>(n_prev, ws, out);
}

// Round 4
// 71.342 us; speedup vs baseline: 1.0217x; 1.0016x over previous
//
#include <hip/hip_runtime.h>
#include <cmath>

#define D 4096

typedef float fvec4 __attribute__((ext_vector_type(4)));

__device__ __forceinline__ float wave_reduce_sum(float v) {
#pragma unroll
    for (int off = 32; off > 0; off >>= 1)
        v += __shfl_down(v, off, 64);
    return v;
}

__device__ __forceinline__ float sigmoidf(float x) {
    return 1.0f / (1.0f + expf(-x));
}

// ws layout (floats):
//   [0 .. 4095]        q
//   [4096 .. 8191]     k (already scaled by 1/sqrt(D))
//   [8192 .. 12287]    v
//   [12288 .. 16383]   o = sigmoid(w_o@x + b_o)
//   [16384]            raw i dot (w_i@x + b_i)
//   [16385]            raw f dot (w_f@x + b_f)
//   [16386]            kq = k . q
//   [16387]            npq = n_prev . q
//   [16388 .. 20483]   cprevq[row] = c_prev[row,:] . q

// Kernel A: 4 fused matvecs (q,k,v,o) + i/f row dots. One wave per row.
// L3 policy: w_q/w_k/w_v (192 MB) cacheable -> stay Infinity-Cache resident
// across graph replays; w_o explicitly nontemporal (streamed from HBM) so the
// protected set fits in the 256 MB L3 alongside transient c-traffic.
__global__ __launch_bounds__(256) void gates_kernel(
    const float* __restrict__ x,
    const float* __restrict__ wq, const float* __restrict__ bq,
    const float* __restrict__ wk, const float* __restrict__ bk,
    const float* __restrict__ wv, const float* __restrict__ bv,
    const float* __restrict__ wi, const float* __restrict__ bi,
    const float* __restrict__ wf, const float* __restrict__ bfv,
    const float* __restrict__ wo, const float* __restrict__ bo,
    float* __restrict__ ws)
{
    __shared__ float xs[D];
    const int tid = threadIdx.x;
    fvec4* xs4 = (fvec4*)xs;
    const fvec4* x4 = (const fvec4*)x;
#pragma unroll
    for (int i = 0; i < 4; ++i) xs4[tid + i * 256] = x4[tid + i * 256];
    __syncthreads();

    const int wave = tid >> 6;
    const int lane = tid & 63;

    if (blockIdx.x == 4096) {
        // i_t and f_t raw dots (rows of w_i, w_f)
        if (wave < 2) {
            const fvec4* W4 = (const fvec4*)(wave == 0 ? wi : wf);
            float acc = 0.f;
#pragma unroll
            for (int it = 0; it < 16; ++it) {
                fvec4 w = W4[it * 64 + lane];
                fvec4 xv = xs4[it * 64 + lane];
                acc += w.x * xv.x + w.y * xv.y + w.z * xv.z + w.w * xv.w;
            }
            acc = wave_reduce_sum(acc);
            if (lane == 0) {
                float b = (wave == 0) ? bi[0] : bfv[0];
                ws[16384 + wave] = acc + b;
            }
        }
        return;
    }

    const int rid = blockIdx.x * 4 + wave;     // [0, 16384)
    const int m = rid >> 12;                   // which matrix
    const int row = rid & 4095;
    const float* W = (m == 0) ? wq : (m == 1) ? wk : (m == 2) ? wv : wo;
    const fvec4* W4 = (const fvec4*)(W + (size_t)row * D);

    float acc0 = 0.f, acc1 = 0.f;
    if (m == 3) {
        // w_o: streamed, evict-early (sacrificed matrix)
#pragma unroll
        for (int it = 0; it < 16; it += 2) {
            fvec4 w0 = __builtin_nontemporal_load(&W4[it * 64 + lane]);
            fvec4 w1 = __builtin_nontemporal_load(&W4[(it + 1) * 64 + lane]);
            fvec4 xv0 = xs4[it * 64 + lane];
            fvec4 xv1 = xs4[(it + 1) * 64 + lane];
            acc0 += w0.x * xv0.x + w0.y * xv0.y + w0.z * xv0.z + w0.w * xv0.w;
            acc1 += w1.x * xv1.x + w1.y * xv1.y + w1.z * xv1.z + w1.w * xv1.w;
        }
    } else {
        // w_q/w_k/w_v: cacheable, L3-protected
#pragma unroll
        for (int it = 0; it < 16; it += 2) {
            fvec4 w0 = W4[it * 64 + lane];
            fvec4 w1 = W4[(it + 1) * 64 + lane];
            fvec4 xv0 = xs4[it * 64 + lane];
            fvec4 xv1 = xs4[(it + 1) * 64 + lane];
            acc0 += w0.x * xv0.x + w0.y * xv0.y + w0.z * xv0.z + w0.w * xv0.w;
            acc1 += w1.x * xv1.x + w1.y * xv1.y + w1.z * xv1.z + w1.w * xv1.w;
        }
    }
    float acc = wave_reduce_sum(acc0 + acc1);
    if (lane == 0) {
        if (m == 0)      ws[row]         = acc + bq[row];
        else if (m == 1) ws[4096 + row]  = (acc + bk[row]) * 0.015625f; // 1/sqrt(4096)
        else if (m == 2) ws[8192 + row]  = acc + bv[row];
        else             ws[12288 + row] = sigmoidf(acc + bo[row]);
    }
}

// Kernel B: c_t = f*c_prev + i*v(x)k  streamed; fused per-row c_prev.q dot.
// c_prev/c_out NONTEMPORAL so streaming traffic does not evict the protected
// weight matrices from L3. Extra block computes kq and n_prev.q scalars.
__global__ __launch_bounds__(256) void cell_kernel(
    const float* __restrict__ c_prev,
    const float* __restrict__ n_prev,
    float* __restrict__ ws,
    float* __restrict__ c_out)
{
    const int tid = threadIdx.x;
    const int wave = tid >> 6;
    const int lane = tid & 63;

    if (blockIdx.x == 1024) {
        __shared__ float red[8];
        const fvec4* q4 = (const fvec4*)ws;
        const fvec4* k4 = (const fvec4*)(ws + D);
        const fvec4* np4 = (const fvec4*)n_prev;
        float kq = 0.f, npq = 0.f;
#pragma unroll
        for (int i = 0; i < 4; ++i) {
            int j = tid + i * 256;
            fvec4 q = q4[j], k = k4[j], np = np4[j];
            kq  += k.x * q.x + k.y * q.y + k.z * q.z + k.w * q.w;
            npq += np.x * q.x + np.y * q.y + np.z * q.z + np.w * q.w;
        }
        kq = wave_reduce_sum(kq);
        npq = wave_reduce_sum(npq);
        if (lane == 0) { red[wave] = kq; red[4 + wave] = npq; }
        __syncthreads();
        if (tid == 0) {
            ws[16386] = red[0] + red[1] + red[2] + red[3];
            ws[16387] = red[4] + red[5] + red[6] + red[7];
        }
        return;
    }

    __shared__ float ks[D];
    __shared__ float qs[D];
    fvec4* ks4 = (fvec4*)ks;
    fvec4* qs4 = (fvec4*)qs;
    const fvec4* k4g = (const fvec4*)(ws + D);
    const fvec4* q4g = (const fvec4*)ws;
#pragma unroll
    for (int i = 0; i < 4; ++i) {
        ks4[tid + i * 256] = k4g[tid + i * 256];
        qs4[tid + i * 256] = q4g[tid + i * 256];
    }
    __syncthreads();

    const float i_t = expf(ws[16384]);
    const float f_t = sigmoidf(ws[16385]);

    const int row = blockIdx.x * 4 + wave;     // [0, 4096)
    const float vr = ws[8192 + row] * i_t;     // i_t * v[row]
    const fvec4* cp4 = (const fvec4*)(c_prev + (size_t)row * D);
    fvec4* co4 = (fvec4*)(c_out + (size_t)row * D);
    float dot = 0.f;
#pragma unroll
    for (int it = 0; it < 16; ++it) {
        int j = it * 64 + lane;
        fvec4 cp = __builtin_nontemporal_load(&cp4[j]);
        fvec4 kk = ks4[j];
        fvec4 qq = qs4[j];
        fvec4 ct;
        ct.x = f_t * cp.x + vr * kk.x;
        ct.y = f_t * cp.y + vr * kk.y;
        ct.z = f_t * cp.z + vr * kk.z;
        ct.w = f_t * cp.w + vr * kk.w;
        __builtin_nontemporal_store(ct, &co4[j]);
        dot += cp.x * qq.x + cp.y * qq.y + cp.z * qq.z + cp.w * qq.w;
    }
    dot = wave_reduce_sum(dot);
    if (lane == 0) ws[16388 + row] = dot;
}

// Kernel C: n_t, h_t (4096 threads)
__global__ __launch_bounds__(256) void finalize_kernel(
    const float* __restrict__ n_prev,
    const float* __restrict__ ws,
    float* __restrict__ out)
{
    const int idx = blockIdx.x * 256 + threadIdx.x;
    const float i_t = expf(ws[16384]);
    const float f_t = sigmoidf(ws[16385]);
    const float kq  = ws[16386];
    const float npq = ws[16387];
    const float nqt = f_t * npq + i_t * kq;          // n_t . q
    const float inv = 1.0f / fmaxf(fabsf(nqt), 1.0f);

    const float k = ws[4096 + idx];
    const float v = ws[8192 + idx];
    const float o = ws[12288 + idx];
    const float cpq = ws[16388 + idx];

    const float h_tilde = (f_t * cpq + i_t * kq * v) * inv;
    out[idx] = o * h_tilde;                            // h_t
    out[(size_t)4096 + (size_t)D * D + idx] = f_t * n_prev[idx] + i_t * k;  // n_t
}

extern "C" void kernel_launch(void* const* d_in, const int* in_sizes, int n_in,
                              void* d_out, int out_size, void* d_ws, size_t ws_size,
                              hipStream_t stream)
{
    const float* x      = (const float*)d_in[0];
    const float* c_prev = (const float*)d_in[1];
    const float* n_prev = (const float*)d_in[2];
    const float* wq = (const float*)d_in[3];  const float* bq  = (const float*)d_in[4];
    const float* wk = (const float*)d_in[5];  const float* bk  = (const float*)d_in[6];
    const float* wv = (const float*)d_in[7];  const float* bv  = (const float*)d_in[8];
    const float* wi = (const float*)d_in[9];  const float* bi  = (const float*)d_in[10];
    const float* wf = (const float*)d_in[11]; const float* bfv = (const float*)d_in[12];
    const float* wo = (const float*)d_in[13]; const float* bo  = (const float*)d_in[14];
    float* out = (float*)d_out;
    float* ws  = (float*)d_ws;

    gates_kernel<<<dim3(4097), dim3(256), 0, stream>>>(
        x, wq, bq, wk, bk, wv, bv, wi, bi, wf, bfv, wo, bo, ws);
    cell_kernel<<<dim3(1025), dim3(256), 0, stream>>>(c_prev, n_prev, ws, out + D);
    finalize_kernel<<<dim3(16), dim3(256), 0, stream>>>(n_prev, ws, out);
}